// Round 2
// baseline (691.292 us; speedup 1.0000x reference)
//
#include <hip/hip_runtime.h>

#define NPTS 12288
#define DIMS 8
#define EPS2 0.25f
#define MINS 5
#define TI   256            // i-points per block (1 per thread)
#define SUBT 256            // j-subtile staged in LDS
#define NJB  16             // j-chunks (grid.y)
#define JCHUNK (NPTS / NJB) // 768
#define NIB  (NPTS / TI)    // 48
#define SENT NPTS

// ---------------- lock-free union-find (device-scope atomics) ----------------

__device__ __forceinline__ int uf_load(int* p, int i) {
  return __hip_atomic_load(&p[i], __ATOMIC_RELAXED, __HIP_MEMORY_SCOPE_AGENT);
}

__device__ int uf_find(int* parent, int v) {
  int p = uf_load(parent, v);
  while (p != v) {
    int gp = uf_load(parent, p);
    if (gp != p) {
      __hip_atomic_store(&parent[v], gp, __ATOMIC_RELAXED, __HIP_MEMORY_SCOPE_AGENT);
    }
    v = p; p = gp;
  }
  return v;
}

__device__ void uf_union(int* parent, int a, int b) {
  while (true) {
    a = uf_find(parent, a);
    b = uf_find(parent, b);
    if (a == b) return;
    int lo = min(a, b), hi = max(a, b);
    int old = atomicCAS(&parent[hi], hi, lo);  // hook larger root under smaller
    if (old == hi) return;
    a = lo; b = hi;
  }
}

// identical d2 expression everywhere so all passes agree bit-exactly
__device__ __forceinline__ float dist2(const float* xi, const float4& a, const float4& b,
                                       float sqi, float sqj) {
  float dot = 0.f;
  dot = fmaf(xi[0], a.x, dot); dot = fmaf(xi[1], a.y, dot);
  dot = fmaf(xi[2], a.z, dot); dot = fmaf(xi[3], a.w, dot);
  dot = fmaf(xi[4], b.x, dot); dot = fmaf(xi[5], b.y, dot);
  dot = fmaf(xi[6], b.z, dot); dot = fmaf(xi[7], b.w, dot);
  return (sqi + sqj) - 2.0f * dot;
}

// ---------------- kernels ----------------

__global__ __launch_bounds__(256) void k_init(const float* __restrict__ X,
                                              float* __restrict__ sq,
                                              int* __restrict__ density,
                                              int* __restrict__ hook) {
  int i = blockIdx.x * blockDim.x + threadIdx.x;
  if (i >= NPTS) return;
  float s = 0.f;
#pragma unroll
  for (int d = 0; d < DIMS; d++) { float x = X[i * DIMS + d]; s = fmaf(x, x, s); }
  sq[i] = s;
  density[i] = 0;
  hook[i] = i;
}

__global__ __launch_bounds__(256) void k_density(const float* __restrict__ X,
                                                 const float* __restrict__ sq,
                                                 int* __restrict__ density) {
  __shared__ float4 xs[SUBT][2];
  __shared__ float sqs[SUBT];
  int t = threadIdx.x;
  int i = blockIdx.x * TI + t;
  float xi[DIMS];
#pragma unroll
  for (int d = 0; d < DIMS; d++) xi[d] = X[i * DIMS + d];
  float sqi = sq[i];
  int j0 = blockIdx.y * JCHUNK;
  int count = 0;
  for (int js = 0; js < JCHUNK; js += SUBT) {
    __syncthreads();
    {
      int j = j0 + js + t;
      xs[t][0] = ((const float4*)X)[j * 2];
      xs[t][1] = ((const float4*)X)[j * 2 + 1];
      sqs[t] = sq[j];
    }
    __syncthreads();
#pragma unroll 4
    for (int jj = 0; jj < SUBT; jj++) {
      float d2 = dist2(xi, xs[jj][0], xs[jj][1], sqi, sqs[jj]);
      count += (d2 <= EPS2) ? 1 : 0;
    }
  }
  atomicAdd(&density[i], count);
}

// hook[i] = min(i, min core-neighbor index) -- pure dense pass, one atomicMin/row/chunk
__global__ __launch_bounds__(256) void k_hook(const float* __restrict__ X,
                                              const float* __restrict__ sq,
                                              const int* __restrict__ density,
                                              int* __restrict__ hook) {
  __shared__ float4 xs[SUBT][2];
  __shared__ float sqs[SUBT];
  __shared__ int dns[SUBT];
  int t = threadIdx.x;
  int i = blockIdx.x * TI + t;
  float xi[DIMS];
#pragma unroll
  for (int d = 0; d < DIMS; d++) xi[d] = X[i * DIMS + d];
  float sqi = sq[i];
  int j0 = blockIdx.y * JCHUNK;
  int m = SENT;
  for (int js = 0; js < JCHUNK; js += SUBT) {
    __syncthreads();
    {
      int j = j0 + js + t;
      xs[t][0] = ((const float4*)X)[j * 2];
      xs[t][1] = ((const float4*)X)[j * 2 + 1];
      sqs[t] = sq[j];
      dns[t] = density[j];
    }
    __syncthreads();
#pragma unroll 4
    for (int jj = 0; jj < SUBT; jj++) {
      float d2 = dist2(xi, xs[jj][0], xs[jj][1], sqi, sqs[jj]);
      if (d2 <= EPS2 && dns[jj] >= MINS) m = min(m, j0 + js + jj);
    }
  }
  if (m < SENT) atomicMin(&hook[i], m);
}

// chase the static hook forest (read-only, strictly decreasing => acyclic)
__global__ __launch_bounds__(256) void k_compress(const int* __restrict__ density,
                                                  const int* __restrict__ hook,
                                                  int* __restrict__ L0,
                                                  int* __restrict__ parent) {
  int i = blockIdx.x * blockDim.x + threadIdx.x;
  if (i >= NPTS) return;
  if (density[i] >= MINS) {
    int v = i;
    int h = hook[v];
    while (h != v) { v = h; h = hook[v]; }
    L0[i] = v;
    parent[i] = v;   // UF trees start as the compressed forest (depth <= 1)
  } else {
    L0[i] = i;
    parent[i] = i;
  }
}

// union only forest-crossing edges, with a small per-row seen-label cache
__global__ __launch_bounds__(256) void k_merge(const float* __restrict__ X,
                                               const float* __restrict__ sq,
                                               const int* __restrict__ density,
                                               const int* __restrict__ L0,
                                               int* __restrict__ parent) {
  __shared__ float4 xs[SUBT][2];
  __shared__ float sqs[SUBT];
  __shared__ int dns[SUBT];
  __shared__ int lbs[SUBT];
  int t = threadIdx.x;
  int i = blockIdx.x * TI + t;
  bool rowActive = (density[i] >= MINS);
  int myL = L0[i];
  int s0 = myL, s1 = myL, s2 = myL;   // seen-label cache
  float xi[DIMS];
#pragma unroll
  for (int d = 0; d < DIMS; d++) xi[d] = X[i * DIMS + d];
  float sqi = sq[i];
  int j0 = blockIdx.y * JCHUNK;
  for (int js = 0; js < JCHUNK; js += SUBT) {
    __syncthreads();
    {
      int j = j0 + js + t;
      xs[t][0] = ((const float4*)X)[j * 2];
      xs[t][1] = ((const float4*)X)[j * 2 + 1];
      sqs[t] = sq[j];
      dns[t] = density[j];
      lbs[t] = L0[j];
    }
    __syncthreads();
    if (!rowActive) continue;
#pragma unroll 4
    for (int jj = 0; jj < SUBT; jj++) {
      float d2 = dist2(xi, xs[jj][0], xs[jj][1], sqi, sqs[jj]);
      int lj = lbs[jj];
      if (d2 <= EPS2 && dns[jj] >= MINS &&
          lj != myL && lj != s0 && lj != s1 && lj != s2) {
        uf_union(parent, i, j0 + js + jj);
        s2 = s1; s1 = s0; s0 = lj;
      }
    }
  }
}

__global__ __launch_bounds__(256) void k_flatten(const int* __restrict__ density,
                                                 int* __restrict__ parent,
                                                 int* __restrict__ root,
                                                 int* __restrict__ is_root) {
  int i = blockIdx.x * blockDim.x + threadIdx.x;
  if (i >= NPTS) return;
  if (density[i] >= MINS) {
    int r = uf_find(parent, i);
    root[i] = r;
    is_root[i] = (r == i) ? 1 : 0;
  } else {
    root[i] = SENT;
    is_root[i] = 0;
  }
}

__global__ __launch_bounds__(256) void k_border(const float* __restrict__ X,
                                                const float* __restrict__ sq,
                                                const int* __restrict__ density,
                                                int* __restrict__ root) {
  __shared__ float4 xs[SUBT][2];
  __shared__ float sqs[SUBT];
  __shared__ int dns[SUBT];
  __shared__ int rts[SUBT];
  int t = threadIdx.x;
  int i = blockIdx.x * TI + t;
  bool rowActive = (density[i] < MINS);
  if (__syncthreads_count(rowActive ? 1 : 0) == 0) return;  // all-core block: skip
  float xi[DIMS];
#pragma unroll
  for (int d = 0; d < DIMS; d++) xi[d] = X[i * DIMS + d];
  float sqi = sq[i];
  int j0 = blockIdx.y * JCHUNK;
  int m = SENT;
  for (int js = 0; js < JCHUNK; js += SUBT) {
    __syncthreads();
    {
      int j = j0 + js + t;
      xs[t][0] = ((const float4*)X)[j * 2];
      xs[t][1] = ((const float4*)X)[j * 2 + 1];
      sqs[t] = sq[j];
      dns[t] = density[j];
      rts[t] = root[j];   // stable for cores after k_flatten
    }
    __syncthreads();
    if (!rowActive) continue;
#pragma unroll 4
    for (int jj = 0; jj < SUBT; jj++) {
      float d2 = dist2(xi, xs[jj][0], xs[jj][1], sqi, sqs[jj]);
      if (d2 <= EPS2 && dns[jj] >= MINS) m = min(m, rts[jj]);
    }
  }
  if (rowActive && m < SENT) atomicMin(&root[i], m);
}

// rank = inclusive cumsum(is_root) - 1 ; one block, wave-scan of per-thread segments
__global__ __launch_bounds__(256) void k_scan(const int* __restrict__ is_root,
                                              int* __restrict__ rank) {
  __shared__ int wsum[4];
  int t = threadIdx.x;
  int lane = t & 63, wid = t >> 6;
  const int SEG = NPTS / 256;  // 48
  int base = t * SEG;
  int s = 0;
#pragma unroll 4
  for (int k = 0; k < SEG; k++) s += is_root[base + k];
  int segsum = s;
  // inclusive wave scan
#pragma unroll
  for (int off = 1; off < 64; off <<= 1) {
    int n = __shfl_up(s, off, 64);
    if (lane >= off) s += n;
  }
  if (lane == 63) wsum[wid] = s;
  __syncthreads();
  int woff = 0;
  for (int w = 0; w < wid; w++) woff += wsum[w];
  int excl = woff + s - segsum;  // exclusive prefix before my segment
  int run = excl;
#pragma unroll 4
  for (int k = 0; k < SEG; k++) {
    run += is_root[base + k];
    rank[base + k] = run - 1;
  }
}

__global__ __launch_bounds__(256) void k_final(const int* __restrict__ root,
                                               const int* __restrict__ rank,
                                               float* __restrict__ out) {
  int i = blockIdx.x * blockDim.x + threadIdx.x;
  if (i >= NPTS) return;
  int r = root[i];
  out[i] = (r < SENT) ? (float)rank[r] : -1.0f;
}

// ---------------- launch ----------------

extern "C" void kernel_launch(void* const* d_in, const int* in_sizes, int n_in,
                              void* d_out, int out_size, void* d_ws, size_t ws_size,
                              hipStream_t stream) {
  const float* X = (const float*)d_in[0];
  float* out = (float*)d_out;

  char* ws = (char*)d_ws;
  float* sq      = (float*)(ws);
  int*   density = (int*)(ws + 4 * NPTS);
  int*   parent  = (int*)(ws + 8 * NPTS);
  int*   root    = (int*)(ws + 12 * NPTS);
  int*   hook    = (int*)(ws + 16 * NPTS);  // reused as is_root after k_compress
  int*   L0      = (int*)(ws + 20 * NPTS);  // reused as rank after k_merge
  int*   is_root = hook;   // hook dead after k_compress
  int*   rank    = L0;     // L0 dead after k_merge

  dim3 grid2(NIB, NJB);

  k_init<<<NIB, 256, 0, stream>>>(X, sq, density, hook);
  k_density<<<grid2, 256, 0, stream>>>(X, sq, density);
  k_hook<<<grid2, 256, 0, stream>>>(X, sq, density, hook);
  k_compress<<<NIB, 256, 0, stream>>>(density, hook, L0, parent);
  k_merge<<<grid2, 256, 0, stream>>>(X, sq, density, L0, parent);
  k_flatten<<<NIB, 256, 0, stream>>>(density, parent, root, is_root);
  k_border<<<grid2, 256, 0, stream>>>(X, sq, density, root);
  k_scan<<<1, 256, 0, stream>>>(is_root, rank);
  k_final<<<NIB, 256, 0, stream>>>(root, rank, out);
}